// Round 19
// baseline (111.272 us; speedup 1.0000x reference)
//
#include <hip/hip_runtime.h>

// ---------------------------------------------------------------------------
// ReliabilityGatedCrossAttention — fp16 MFMA pipeline, gfx950.  R19.
//
// R18 (103.9us, best) + one change: attn_mean stores were 64B-segment
// uncoalesced (4x64B per instruction, ~2.2TB/s).  R19: stage the block's
// [64 q][256 k] mean tile in LDS as fp16 (33KB), then a fully-coalesced
// fp32 write pass (1KB per wave-instruction).  LDS 74.7KB -> 2 blocks/CU.
// ---------------------------------------------------------------------------

typedef __attribute__((ext_vector_type(8))) _Float16 half8;
typedef __attribute__((ext_vector_type(4))) _Float16 half4;
typedef __attribute__((ext_vector_type(2))) __fp16 fp16x2;   // cvt_pkrtz result type
typedef __attribute__((ext_vector_type(4))) float f32x4;

#define MFMAH32(A, B, C) __builtin_amdgcn_mfma_f32_16x16x32_f16((A), (B), (C), 0, 0, 0)
#define MFMAH16(A, B, C) __builtin_amdgcn_mfma_f32_16x16x16f16((A), (B), (C), 0, 0, 0)

__device__ __forceinline__ unsigned short f2h(float f) {
    union { _Float16 h; unsigned short u; } c; c.h = (_Float16)f; return c.u;
}
__device__ __forceinline__ float h2f(unsigned short u) {
    union { unsigned short u; _Float16 h; } c; c.u = u; return (float)c.h;
}
__device__ __forceinline__ half8 ldh8(const unsigned short* p) {
    return *reinterpret_cast<const half8*>(p);
}
__device__ __forceinline__ half4 ldh4(const unsigned short* p) {
    return *reinterpret_cast<const half4*>(p);
}
__device__ __forceinline__ half4 pk4(float a, float b, float c, float d) {
    union { fp16x2 h2[2]; half4 h4; } u;
    u.h2[0] = __builtin_amdgcn_cvt_pkrtz(a, b);
    u.h2[1] = __builtin_amdgcn_cvt_pkrtz(c, d);
    return u.h4;
}
__device__ __forceinline__ void gld16(const unsigned short* g, unsigned short* l) {
    __builtin_amdgcn_global_load_lds(
        (const __attribute__((address_space(1))) unsigned int*)g,
        (__attribute__((address_space(3))) unsigned int*)l, 16, 0, 0);
}

// ---------------------------------------------------------------------------
// 1. Weights -> fp16, transposed [n][k]
// ---------------------------------------------------------------------------
__global__ void wsplit_kernel(const float* __restrict__ Wq, const float* __restrict__ Wk,
                              const float* __restrict__ Wv, const float* __restrict__ Wo,
                              unsigned short* __restrict__ WT) {
    int e = blockIdx.x * 256 + threadIdx.x;
    int m = e >> 16;
    int idx = e & 65535;
    int k = idx >> 8, n = idx & 255;
    const float* W = (m == 0) ? Wq : (m == 1) ? Wk : (m == 2) ? Wv : Wo;
    WT[m * 65536 + n * 256 + k] = f2h(W[idx]);
}

// ---------------------------------------------------------------------------
// Weight-staged fp16 GEMM core.  STAGE_W: 512-thr.  STAGE_W8: 256-thr.
// ---------------------------------------------------------------------------
#define STAGE_W(dst_, src_, kt_) do {                                               \
    _Pragma("unroll")                                                               \
    for (int j_ = 0; j_ < 4; ++j_) {                                                \
        int s_ = w * 4 + j_;                                                        \
        int rowl_ = 8 * s_ + (l >> 3);                                              \
        int so_ = rowl_ * 256 + (kt_) * 64 + (((l & 7) ^ (rowl_ & 7)) << 3);        \
        gld16(&(src_)[so_], &(dst_)[s_ * 512]);                                     \
    }                                                                               \
} while (0)

#define STAGE_W8(dst_, src_, kt_) do {                                              \
    _Pragma("unroll")                                                               \
    for (int j_ = 0; j_ < 8; ++j_) {                                                \
        int s_ = w * 8 + j_;                                                        \
        int rowl_ = 8 * s_ + (l >> 3);                                              \
        int so_ = rowl_ * 256 + (kt_) * 64 + (((l & 7) ^ (rowl_ & 7)) << 3);        \
        gld16(&(src_)[so_], &(dst_)[s_ * 512]);                                     \
    }                                                                               \
} while (0)

#define GEMM_TILE(buf_, kt_) do {                                                   \
    _Pragma("unroll")                                                               \
    for (int ksl_ = 0; ksl_ < 2; ++ksl_) {                                          \
        _Pragma("unroll")                                                           \
        for (int n_ = 0; n_ < 16; ++n_) {                                           \
            int r_ = n_ * 16 + l15;                                                 \
            int idx_ = r_ * 64 + ((((ksl_)*4 + lg) ^ (r_ & 7)) << 3);               \
            half8 b_ = ldh8(&(buf_)[idx_]);                                         \
            acc[n_] = MFMAH32(ah[(kt_) * 2 + ksl_], b_, acc[n_]);                   \
        }                                                                           \
    }                                                                               \
} while (0)

// ---------------------------------------------------------------------------
// 2. Projections (job 0:Q, 1:K, 2:V).  512 thr, 128 rows/block, grid (64,3).
// ---------------------------------------------------------------------------
__global__ __launch_bounds__(512, 1) void proj3_kernel(
    const float* __restrict__ query, const float* __restrict__ kv,
    const float* __restrict__ rel, const unsigned short* __restrict__ WT,
    const float* __restrict__ bq, const float* __restrict__ bk, const float* __restrict__ bv,
    unsigned short* __restrict__ Qh, unsigned short* __restrict__ Kh,
    unsigned short* __restrict__ Vtmp) {
    const int job = blockIdx.y;
    const float* X = (job == 0) ? query : kv;
    const unsigned short* wg = WT + job * 65536;
    const float* bias = (job == 0) ? bq : (job == 1) ? bk : bv;
    const float* rs = (job == 0) ? nullptr : rel;
    unsigned short* oh = (job == 0) ? Qh : (job == 1) ? Kh : Vtmp;

    __shared__ __align__(16) unsigned short wlds[2][256 * 64];

    const int w = threadIdx.x >> 6, l = threadIdx.x & 63;
    const int l15 = l & 15, lg = l >> 4;
    const int arow = blockIdx.x * 128 + w * 16 + l15;

    half8 ah[8];
#pragma unroll
    for (int ks = 0; ks < 8; ++ks) {
        const float* p = &X[arow * 256 + ks * 32 + lg * 8];
        float4 f0 = *reinterpret_cast<const float4*>(p);
        float4 f1 = *reinterpret_cast<const float4*>(p + 4);
        half8 t;
        t[0] = (_Float16)f0.x; t[1] = (_Float16)f0.y; t[2] = (_Float16)f0.z; t[3] = (_Float16)f0.w;
        t[4] = (_Float16)f1.x; t[5] = (_Float16)f1.y; t[6] = (_Float16)f1.z; t[7] = (_Float16)f1.w;
        ah[ks] = t;
    }
    f32x4 acc[16];
#pragma unroll
    for (int n = 0; n < 16; ++n) acc[n] = (f32x4){0.f, 0.f, 0.f, 0.f};

    STAGE_W(wlds[0], wg, 0);
    __syncthreads();
#pragma unroll
    for (int kt = 0; kt < 4; ++kt) {
        const int cur = kt & 1, nx = cur ^ 1;
        if (kt < 3) STAGE_W(wlds[nx], wg, kt + 1);
        GEMM_TILE(wlds[cur], kt);
        __syncthreads();
    }

    const int orow0 = blockIdx.x * 128 + w * 16 + lg * 4;
    float rsv[4];
#pragma unroll
    for (int r = 0; r < 4; ++r) rsv[r] = rs ? rs[orow0 + r] : 1.0f;
#pragma unroll
    for (int n = 0; n < 16; ++n) {
        const int col = n * 16 + l15;
        const float bn = bias[col];
#pragma unroll
        for (int r = 0; r < 4; ++r)
            oh[(orow0 + r) * 256 + col] = f2h((acc[n][r] + bn) * rsv[r]);
    }
}

// ---------------------------------------------------------------------------
// 3. Transpose V: Vtmp [b][k][256 d] -> Vt [b][st=k/16][256 d][16 k]
// ---------------------------------------------------------------------------
__global__ void transpose_v_kernel(const unsigned short* __restrict__ Vtmp,
                                   unsigned short* __restrict__ Vt) {
    __shared__ unsigned short tile[16][264];
    const int st = blockIdx.x, b = blockIdx.y;
    const int t = threadIdx.x;
#pragma unroll
    for (int it = 0; it < 4; ++it) {
        int idx = it * 256 + t;              // ushort4 units, 1024 total
        int kr = idx >> 6;
        int d4 = (idx & 63) * 4;
        ushort4 v = *reinterpret_cast<const ushort4*>(
            &Vtmp[(size_t)(b * 2048 + st * 16 + kr) * 256 + d4]);
        tile[kr][d4 + 0] = v.x; tile[kr][d4 + 1] = v.y;
        tile[kr][d4 + 2] = v.z; tile[kr][d4 + 3] = v.w;
    }
    __syncthreads();
    {
        const int d = t;
        unsigned int u[8];
#pragma unroll
        for (int k2 = 0; k2 < 8; ++k2)
            u[k2] = (unsigned int)tile[k2 * 2][d] | ((unsigned int)tile[k2 * 2 + 1][d] << 16);
        uint4* dst = reinterpret_cast<uint4*>(&Vt[((size_t)(b * 128 + st) * 256 + d) * 16]);
        dst[0] = (uint4){u[0], u[1], u[2], u[3]};
        dst[1] = (uint4){u[4], u[5], u[6], u[7]};
    }
}

// ---------------------------------------------------------------------------
// 4. Attention pass 1 (R14-proven depth-1).  Grid 512 = 4b x 64qt(32) x 2kh.
// ---------------------------------------------------------------------------
__global__ __launch_bounds__(512, 4) void attn_pass1(
    const unsigned short* __restrict__ Qh, const unsigned short* __restrict__ Kh,
    const unsigned short* __restrict__ Vt, const float* __restrict__ rel,
    float* __restrict__ po_a, float* __restrict__ po_b, float* __restrict__ ps) {
    const int bid = blockIdx.x;                       // 0..511
    const int sw = (bid & 7) * 64 + (bid >> 3);       // XCD batch-locality
    const int b = sw >> 7;                            // 0..3
    const int rem = sw & 127;                         // 64qt x 2kh
    const int kh = rem & 1;
    const int q0 = (rem >> 1) * 32;                   // 32-row q tile
    const int tid = threadIdx.x;
    const int w = tid >> 6, h = w & 3, ks = w >> 2;
    const int l = tid & 63, l15 = l & 15, lg = l >> 4;
    const float C2 = 0.18033688011112042f;            // 0.125 * log2(e)

    __shared__ __align__(16) unsigned short ldsK[8][2][1024];   // 32KB
    __shared__ float rel_lr[2048];                              // 8KB
    __shared__ float ssum_sh[2][4][2][16];                      // 1KB

    {   // lr = log2(clamp(rel)): 512 thr x 4 floats
        float4 v = reinterpret_cast<const float4*>(&rel[b * 2048])[tid];
        float* d = &rel_lr[tid * 4];
        d[0] = log2f(fmaxf(v.x, 1e-6f)); d[1] = log2f(fmaxf(v.y, 1e-6f));
        d[2] = log2f(fmaxf(v.z, 1e-6f)); d[3] = log2f(fmaxf(v.w, 1e-6f));
    }

    half8 qf[2][2];                                   // [qs][kd] B-frags
#pragma unroll
    for (int qs = 0; qs < 2; ++qs)
#pragma unroll
        for (int kd = 0; kd < 2; ++kd)
            qf[qs][kd] = ldh8(&Qh[(b * 2048 + q0 + qs * 16 + l15) * 256 +
                                  h * 64 + kd * 32 + lg * 8]);
    __syncthreads();

    const int st0 = kh * 64 + ks * 32;                // 16-row step units

    size_t kb_[2];
    {
        const int swzK = ((l & 7) ^ ((l >> 3) & 7)) << 3;
#pragma unroll
        for (int j = 0; j < 2; ++j) {
            int kr = j * 8 + (l >> 3);
            kb_[j] = (size_t)(b * 2048 + st0 * 16 + kr) * 256 + h * 64 + swzK;
        }
    }
    size_t va_[4];
#pragma unroll
    for (int dc = 0; dc < 4; ++dc)
        va_[dc] = ((size_t)((b * 128 + st0) * 256) + h * 64 + dc * 16 + l15) * 16 + lg * 4;

    unsigned short* myK = &ldsK[w][0][0];
    const int kOff0 = l15 * 64 + ((lg ^ (l15 & 7)) << 3);
    const int kOff1 = l15 * 64 + (((4 + lg) ^ (l15 & 7)) << 3);

#define STGK(buf_, i_) do {                                                         \
    gld16(&Kh[kb_[0] + (size_t)(i_) * 4096], &myK[(buf_) * 1024]);                  \
    gld16(&Kh[kb_[1] + (size_t)(i_) * 4096], &myK[(buf_) * 1024 + 512]);            \
} while (0)
#define VLOADM(dst_, i_) do {                                                       \
    dst_[0] = ldh4(&Vt[va_[0] + (size_t)(i_) * 4096]);                              \
    dst_[1] = ldh4(&Vt[va_[1] + (size_t)(i_) * 4096]);                              \
    dst_[2] = ldh4(&Vt[va_[2] + (size_t)(i_) * 4096]);                              \
    dst_[3] = ldh4(&Vt[va_[3] + (size_t)(i_) * 4096]);                              \
} while (0)

    float ssum0 = 0.f, ssum1 = 0.f;
    f32x4 oacc0[4], oacc1[4];
#pragma unroll
    for (int dc = 0; dc < 4; ++dc) {
        oacc0[dc] = (f32x4){0.f, 0.f, 0.f, 0.f};
        oacc1[dc] = (f32x4){0.f, 0.f, 0.f, 0.f};
    }

#define COMPUTE(step_, BUF_, VF_) do {                                              \
    half8 kf0 = ldh8(&myK[(BUF_) * 1024 + kOff0]);                                  \
    half8 kf1 = ldh8(&myK[(BUF_) * 1024 + kOff1]);                                  \
    f32x4 a0 = (f32x4){0.f, 0.f, 0.f, 0.f}, a1 = a0;                                \
    a0 = MFMAH32(kf0, qf[0][0], a0); a0 = MFMAH32(kf1, qf[0][1], a0);               \
    a1 = MFMAH32(kf0, qf[1][0], a1); a1 = MFMAH32(kf1, qf[1][1], a1);               \
    float4 lr4 = *reinterpret_cast<const float4*>(                                  \
        &rel_lr[(st0 + (step_)) * 16 + lg * 4]);                                    \
    float p00 = exp2f(__builtin_fmaf(a0[0], C2, lr4.x));                            \
    float p01 = exp2f(__builtin_fmaf(a0[1], C2, lr4.y));                            \
    float p02 = exp2f(__builtin_fmaf(a0[2], C2, lr4.z));                            \
    float p03 = exp2f(__builtin_fmaf(a0[3], C2, lr4.w));                            \
    float p10 = exp2f(__builtin_fmaf(a1[0], C2, lr4.x));                            \
    float p11 = exp2f(__builtin_fmaf(a1[1], C2, lr4.y));                            \
    float p12 = exp2f(__builtin_fmaf(a1[2], C2, lr4.z));                            \
    float p13 = exp2f(__builtin_fmaf(a1[3], C2, lr4.w));                            \
    ssum0 += (p00 + p01) + (p02 + p03);                                             \
    ssum1 += (p10 + p11) + (p12 + p13);                                             \
    half4 pa0 = pk4(p00, p01, p02, p03);                                            \
    half4 pa1 = pk4(p10, p11, p12, p13);                                            \
    _Pragma("unroll")                                                               \
    for (int dc = 0; dc < 4; ++dc) {                                                \
        oacc0[dc] = MFMAH16(pa0, VF_[dc], oacc0[dc]);                               \
        oacc1[dc] = MFMAH16(pa1, VF_[dc], oacc1[dc]);                               \
    }                                                                               \
} while (0)

    half4 vfa[4], vfb[4];
    STGK(0, 0);
    VLOADM(vfa, 0);
    for (int i = 0; i < 32; i += 2) {
        STGK(1, i + 1);
        VLOADM(vfb, i + 1);
        asm volatile("s_waitcnt vmcnt(6)" ::: "memory");
        __builtin_amdgcn_sched_barrier(0);
        COMPUTE(i, 0, vfa);
        {
            const int nxt = (i + 2 < 32) ? i + 2 : 31;
            STGK(0, nxt);
            VLOADM(vfa, nxt);
        }
        asm volatile("s_waitcnt vmcnt(6)" ::: "memory");
        __builtin_amdgcn_sched_barrier(0);
        COMPUTE(i + 1, 1, vfb);
    }
    asm volatile("s_waitcnt vmcnt(0)" ::: "memory");
#undef STGK
#undef VLOADM
#undef COMPUTE

    float vr0 = ssum0, vr1 = ssum1;
    vr0 += __shfl_xor(vr0, 16); vr0 += __shfl_xor(vr0, 32);
    vr1 += __shfl_xor(vr1, 16); vr1 += __shfl_xor(vr1, 32);

    __syncthreads();                                  // done with ldsK
    if (l < 16) { ssum_sh[ks][h][0][l] = vr0; ssum_sh[ks][h][1][l] = vr1; }
    float* obuf = (float*)&ldsK[0][0][0];             // [32 q][256 d] = 32KB
    if (ks == 1) {
#pragma unroll
        for (int qs = 0; qs < 2; ++qs)
#pragma unroll
            for (int dc = 0; dc < 4; ++dc)
#pragma unroll
                for (int r = 0; r < 4; ++r)
                    obuf[(qs * 16 + lg * 4 + r) * 256 + h * 64 + dc * 16 + l15] =
                        (qs == 0) ? oacc0[dc][r] : oacc1[dc][r];
    }
    __syncthreads();
    if (ks == 0) {
        const int chunk = b * 2 + kh;                 // 0..7
        float* po = (chunk < 2) ? (po_a + (size_t)chunk * 524288)
                                : (po_b + (size_t)(chunk - 2) * 524288);
#pragma unroll
        for (int qs = 0; qs < 2; ++qs)
#pragma unroll
            for (int dc = 0; dc < 4; ++dc)
#pragma unroll
                for (int r = 0; r < 4; ++r) {
                    const int d = h * 64 + dc * 16 + l15;
                    const int q = qs * 16 + lg * 4 + r;
                    const float mine = (qs == 0) ? oacc0[dc][r] : oacc1[dc][r];
                    po[(size_t)(q0 + q) * 256 + d] = mine + obuf[q * 256 + d];
                }
        if (l < 16) {
            ps[(chunk * 4 + h) * 2048 + q0 + l] =
                ssum_sh[0][h][0][l] + ssum_sh[1][h][0][l];
            ps[(chunk * 4 + h) * 2048 + q0 + 16 + l] =
                ssum_sh[0][h][1][l] + ssum_sh[1][h][1][l];
        }
    }
}

// ---------------------------------------------------------------------------
// 5. Combine k-half partials: AO = (po0+po1)/s (fp16), sinv_ws = 1/s.
// ---------------------------------------------------------------------------
__global__ __launch_bounds__(256) void combine_kernel(
    const float* __restrict__ po_a, const float* __restrict__ po_b,
    const float* __restrict__ ps, unsigned short* __restrict__ AO,
    float* __restrict__ sinv_ws) {
    const int t = blockIdx.x * 256 + threadIdx.x;
    const int d4 = t & 63;
    const int bq = t >> 6;
    const int q = bq & 2047;
    const int b = bq >> 11;
    const int d0 = d4 * 4, h = d0 >> 6;
    const int c0 = b * 2, c1 = b * 2 + 1;
    const float* p0 = (c0 < 2) ? po_a + (size_t)c0 * 524288 : po_b + (size_t)(c0 - 2) * 524288;
    const float* p1 = (c1 < 2) ? po_a + (size_t)c1 * 524288 : po_b + (size_t)(c1 - 2) * 524288;
    float4 x = *reinterpret_cast<const float4*>(&p0[(size_t)q * 256 + d0]);
    float4 y = *reinterpret_cast<const float4*>(&p1[(size_t)q * 256 + d0]);
    float s = ps[(c0 * 4 + h) * 2048 + q] + ps[(c1 * 4 + h) * 2048 + q];
    float si = 1.0f / s;
    ushort4 o;
    o.x = f2h((x.x + y.x) * si); o.y = f2h((x.y + y.y) * si);
    o.z = f2h((x.z + y.z) * si); o.w = f2h((x.w + y.w) * si);
    *reinterpret_cast<ushort4*>(&AO[((size_t)(b * 2048 + q)) * 256 + d0]) = o;
    if (d4 == (h << 4)) sinv_ws[(b * 4 + h) * 2048 + q] = si;
}

// ---------------------------------------------------------------------------
// 6. Attention pass 2: attn_mean.  Grid 1024 = 8 kslices x (4b x 32 qt of
//    64 rows); 256 thr = 4 waves = qs.  Head-mean in-register -> fp16 LDS
//    tile [64 q][256 k] -> fully-coalesced fp32 write pass (1KB/wave-instr).
// ---------------------------------------------------------------------------
__global__ __launch_bounds__(256, 2) void attn_mean_kernel(
    const unsigned short* __restrict__ Qh, const unsigned short* __restrict__ Kh,
    const float* __restrict__ rel, const float* __restrict__ sinv_ws,
    float* __restrict__ attn_mean) {
    const int kslice = blockIdx.x >> 7;               // 0..7
    const int inner = blockIdx.x & 127;
    const int sw = (inner & 7) * 16 + (inner >> 3);   // XCD batch-locality
    const int b = sw >> 5;
    const int q0 = (sw & 31) * 64;                    // 64-row q tile
    const int tid = threadIdx.x;
    const int w = tid >> 6;                           // wave = qs (0..3)
    const int l = tid & 63, l15 = l & 15, lg = l >> 4;
    const int kb = b * 2048;
    const float C2 = 0.18033688011112042f;

    __shared__ __align__(16) unsigned short ldsK[2][8192];      // 32KB
    __shared__ float rel_lr[2048];                              // 8KB
    __shared__ __align__(16) unsigned short mstage[64][264];    // 33KB mean tile

    {
        float4 v0 = reinterpret_cast<const float4*>(&rel[b * 2048])[tid * 2];
        float4 v1 = reinterpret_cast<const float4*>(&rel[b * 2048])[tid * 2 + 1];
        float* d = &rel_lr[tid * 8];
        d[0] = log2f(fmaxf(v0.x, 1e-6f)); d[1] = log2f(fmaxf(v0.y, 1e-6f));
        d[2] = log2f(fmaxf(v0.z, 1e-6f)); d[3] = log2f(fmaxf(v0.w, 1e-6f));
        d[4] = log2f(fmaxf(v1.x, 1e-6f)); d[5] = log2f(fmaxf(v1.y, 1e-6f));
        d[6] = log2f(fmaxf(v1.z, 1e-6f)); d[7] = log2f(fmaxf(v1.w, 1e-6f));
    }

    half8 qf[4][2];
    {
        const int qrow = b * 2048 + q0 + w * 16 + l15;
#pragma unroll
        for (int h = 0; h < 4; ++h)
#pragma unroll
            for (int kd = 0; kd < 2; ++kd)
                qf[h][kd] = ldh8(&Qh[qrow * 256 + h * 64 + kd * 32 + lg * 8]);
    }
    float lsi[4][4];
#pragma unroll
    for (int h = 0; h < 4; ++h)
#pragma unroll
        for (int r4 = 0; r4 < 4; ++r4)
            lsi[h][r4] = log2f(sinv_ws[(b * 4 + h) * 2048 + q0 + w * 16 + lg * 4 + r4]) - 2.0f;

    size_t kmb[4];
    {
#pragma unroll
        for (int j = 0; j < 4; ++j) {
            int s_ = w * 4 + j;
            int r_ = 2 * s_ + (l >> 5);
            kmb[j] = (size_t)(kb + r_) * 256 + (((l & 31) ^ (r_ & 7)) << 3);
        }
    }
#define STAGE_KM2(dst_, off_) do {                                                  \
    gld16(&Kh[kmb[0] + (off_)], &(dst_)[(w * 4 + 0) * 512]);                        \
    gld16(&Kh[kmb[1] + (off_)], &(dst_)[(w * 4 + 1) * 512]);                        \
    gld16(&Kh[kmb[2] + (off_)], &(dst_)[(w * 4 + 2) * 512]);                        \
    gld16(&Kh[kmb[3] + (off_)], &(dst_)[(w * 4 + 3) * 512]);                        \
} while (0)

    __syncthreads();

    const int kt0 = kslice * 8;
    size_t moff = (size_t)kt0 * 8192;
    STAGE_KM2(ldsK[0], moff);
    for (int ki = 0; ki < 8; ++ki) {
        const int kt = kt0 + ki;
        const int cur = ki & 1, nx = cur ^ 1;
        if (ki < 7) {
            STAGE_KM2(ldsK[nx], moff + 8192);
            moff += 8192;
            asm volatile("s_waitcnt vmcnt(4)" ::: "memory");
        } else {
            asm volatile("s_waitcnt vmcnt(0)" ::: "memory");
        }
        asm volatile("s_barrier" ::: "memory");       // buf[cur] ready
        __builtin_amdgcn_sched_barrier(0);
#pragma unroll
        for (int kc = 0; kc < 2; ++kc) {
            const int r = kc * 16 + l15;
            const int rx = r & 7;
            f32x4 a[4];
#pragma unroll
            for (int h = 0; h < 4; ++h) {
                half8 kf0 = ldh8(&ldsK[cur][r * 256 + (((h * 8 + lg) ^ rx) << 3)]);
                half8 kf1 = ldh8(&ldsK[cur][r * 256 + (((h * 8 + 4 + lg) ^ rx) << 3)]);
                f32x4 t = (f32x4){0.f, 0.f, 0.f, 0.f};
                t = MFMAH32(qf[h][0], kf0, t);
                t = MFMAH32(qf[h][1], kf1, t);
                a[h] = t;
            }
            const float lr = rel_lr[kt * 32 + kc * 16 + l15];
            const int kcol = ki * 32 + kc * 16 + l15;          // 0..255 in-tile
#pragma unroll
            for (int r4 = 0; r4 < 4; ++r4) {
                float m = exp2f(__builtin_fmaf(a[0][r4], C2, lsi[0][r4]) + lr)
                        + exp2f(__builtin_fmaf(a[1][r4], C2, lsi[1][r4]) + lr)
                        + exp2f(__builtin_fmaf(a[2][r4], C2, lsi[2][r4]) + lr)
                        + exp2f(__builtin_fmaf(a[3][r4], C2, lsi[3][r4]) + lr);
                mstage[w * 16 + lg * 4 + r4][kcol] = f2h(m);
            }
        }
        asm volatile("s_waitcnt lgkmcnt(0)\n\ts_barrier" ::: "memory");  // reads done
    }
#undef STAGE_KM2

    __syncthreads();                                  // mstage complete
    // coalesced write pass: wave writes one full 1KB row per iteration
    {
        const int colb = l * 4;                       // 0..252
#pragma unroll
        for (int rr = 0; rr < 16; ++rr) {
            const int row = rr * 4 + w;
            ushort4 u = *reinterpret_cast<const ushort4*>(&mstage[row][colb]);
            float4 o = (float4){h2f(u.x), h2f(u.y), h2f(u.z), h2f(u.w)};
            *reinterpret_cast<float4*>(
                &attn_mean[(size_t)(b * 2048 + q0 + row) * 2048 + kslice * 256 + colb]) = o;
        }
    }
}

// ---------------------------------------------------------------------------
// 7. out = AO @ Wo + bo.  256 thr, BM=64, grid 128.
// ---------------------------------------------------------------------------
__global__ __launch_bounds__(256, 2) void final_kernel(
    const unsigned short* __restrict__ AO, const unsigned short* __restrict__ WoT,
    const float* __restrict__ bo, float* __restrict__ out) {
    __shared__ __align__(16) unsigned short wlds[2][256 * 64];

    const int w = threadIdx.x >> 6, l = threadIdx.x & 63;
    const int l15 = l & 15, lg = l >> 4;
    const int arow = blockIdx.x * 64 + w * 16 + l15;

    half8 ah[8];
#pragma unroll
    for (int ks = 0; ks < 8; ++ks)
        ah[ks] = ldh8(&AO[arow * 256 + ks * 32 + lg * 8]);
    f32x4 acc[16];
#pragma unroll
    for (int n = 0; n < 16; ++n) acc[n] = (f32x4){0.f, 0.f, 0.f, 0.f};

    STAGE_W8(wlds[0], WoT, 0);
    __syncthreads();
#pragma unroll
    for (int kt = 0; kt < 4; ++kt) {
        const int cur = kt & 1, nx = cur ^ 1;
        if (kt < 3) STAGE_W8(wlds[nx], WoT, kt + 1);
        GEMM_TILE(wlds[cur], kt);
        __syncthreads();
    }

    const int orow0 = blockIdx.x * 64 + w * 16 + lg * 4;
#pragma unroll
    for (int n = 0; n < 16; ++n) {
        const int col = n * 16 + l15;
        const float bn = bo[col];
#pragma unroll
        for (int r = 0; r < 4; ++r)
            out[(orow0 + r) * 256 + col] = acc[n][r] + bn;
    }
}

// ---------------------------------------------------------------------------
extern "C" void kernel_launch(void* const* d_in, const int* in_sizes, int n_in,
                              void* d_out, int out_size, void* d_ws, size_t ws_size,
                              hipStream_t stream) {
    const float* query = (const float*)d_in[0];
    const float* kv    = (const float*)d_in[1];
    const float* rel   = (const float*)d_in[2];
    const float* Wq    = (const float*)d_in[3];
    const float* bq    = (const float*)d_in[4];
    const float* Wk    = (const float*)d_in[5];
    const float* bk    = (const float*)d_in[6];
    const float* Wv    = (const float*)d_in[7];
    const float* bv    = (const float*)d_in[8];
    const float* Wo    = (const float*)d_in[9];
    const float* bo    = (const float*)d_in[10];

    char* ws = (char*)d_ws;
    unsigned short* WT   = (unsigned short*)(ws + 0);          // 512KB
    unsigned short* Qh   = (unsigned short*)(ws + 524288);     // 4MB
    unsigned short* Kh   = (unsigned short*)(ws + 4718592);    // 4MB
    unsigned short* Vtmp = (unsigned short*)(ws + 8912896);    // 4MB (po_a after transpose)
    unsigned short* Vt   = (unsigned short*)(ws + 13107200);   // 4MB
    unsigned short* AO   = (unsigned short*)(ws + 17301504);   // 4MB
    float*          sinv = (float*)(ws + 21495808);            // 128KB
    float*          ps   = (float*)(ws + 21626880);            // 256KB (8 chunks x 4 h)
    float*          po_b = (float*)(ws + 21889024);            // 12MB (chunks 2..7)
    float*          po_a = (float*)Vtmp;                       // chunks 0,1 overlay (4MB)

    float* out = (float*)d_out;
    float* attn_mean = (float*)d_out + 2097152;

    wsplit_kernel<<<1024, 256, 0, stream>>>(Wq, Wk, Wv, Wo, WT);
    proj3_kernel<<<dim3(64, 3), 512, 0, stream>>>(query, kv, rel, WT,
                                                  bq, bk, bv, Qh, Kh, Vtmp);
    transpose_v_kernel<<<dim3(128, 4), 256, 0, stream>>>(Vtmp, Vt);
    attn_pass1<<<512, 512, 0, stream>>>(Qh, Kh, Vt, rel, po_a, po_b, ps);
    combine_kernel<<<2048, 256, 0, stream>>>(po_a, po_b, ps, AO, sinv);
    attn_mean_kernel<<<1024, 256, 0, stream>>>(Qh, Kh, rel, sinv, attn_mean);
    final_kernel<<<128, 256, 0, stream>>>(AO, WT + 3 * 65536, bo, out);
}

// Round 20
// 103.188 us; speedup vs baseline: 1.0783x; 1.0783x over previous
//
#include <hip/hip_runtime.h>

// ---------------------------------------------------------------------------
// ReliabilityGatedCrossAttention — fp16 MFMA pipeline, gfx950.  R20 = R18
// verbatim (measured best, 103.9us).  R19's mean-LDS-staging regressed
// (occupancy halved; attn_mean is exp/VALU-bound, not store-bound) — the
// fourth refuted experiment; consolidating on the proven optimum:
//   * pass1: depth-1 (K gld_lds dbuf + V global->reg 2 sets, vmcnt(6)).
//   * combine + attn_mean(256,4 direct stores): R14's.
//   * final: 256thr / BM=64 / grid 128.
// ---------------------------------------------------------------------------

typedef __attribute__((ext_vector_type(8))) _Float16 half8;
typedef __attribute__((ext_vector_type(4))) _Float16 half4;
typedef __attribute__((ext_vector_type(2))) __fp16 fp16x2;   // cvt_pkrtz result type
typedef __attribute__((ext_vector_type(4))) float f32x4;

#define MFMAH32(A, B, C) __builtin_amdgcn_mfma_f32_16x16x32_f16((A), (B), (C), 0, 0, 0)
#define MFMAH16(A, B, C) __builtin_amdgcn_mfma_f32_16x16x16f16((A), (B), (C), 0, 0, 0)

__device__ __forceinline__ unsigned short f2h(float f) {
    union { _Float16 h; unsigned short u; } c; c.h = (_Float16)f; return c.u;
}
__device__ __forceinline__ float h2f(unsigned short u) {
    union { unsigned short u; _Float16 h; } c; c.u = u; return (float)c.h;
}
__device__ __forceinline__ half8 ldh8(const unsigned short* p) {
    return *reinterpret_cast<const half8*>(p);
}
__device__ __forceinline__ half4 ldh4(const unsigned short* p) {
    return *reinterpret_cast<const half4*>(p);
}
__device__ __forceinline__ half4 pk4(float a, float b, float c, float d) {
    union { fp16x2 h2[2]; half4 h4; } u;
    u.h2[0] = __builtin_amdgcn_cvt_pkrtz(a, b);
    u.h2[1] = __builtin_amdgcn_cvt_pkrtz(c, d);
    return u.h4;
}
__device__ __forceinline__ void gld16(const unsigned short* g, unsigned short* l) {
    __builtin_amdgcn_global_load_lds(
        (const __attribute__((address_space(1))) unsigned int*)g,
        (__attribute__((address_space(3))) unsigned int*)l, 16, 0, 0);
}

// ---------------------------------------------------------------------------
// 1. Weights -> fp16, transposed [n][k]
// ---------------------------------------------------------------------------
__global__ void wsplit_kernel(const float* __restrict__ Wq, const float* __restrict__ Wk,
                              const float* __restrict__ Wv, const float* __restrict__ Wo,
                              unsigned short* __restrict__ WT) {
    int e = blockIdx.x * 256 + threadIdx.x;
    int m = e >> 16;
    int idx = e & 65535;
    int k = idx >> 8, n = idx & 255;
    const float* W = (m == 0) ? Wq : (m == 1) ? Wk : (m == 2) ? Wv : Wo;
    WT[m * 65536 + n * 256 + k] = f2h(W[idx]);
}

// ---------------------------------------------------------------------------
// Weight-staged fp16 GEMM core.  STAGE_W: 512-thr.  STAGE_W8: 256-thr.
// ---------------------------------------------------------------------------
#define STAGE_W(dst_, src_, kt_) do {                                               \
    _Pragma("unroll")                                                               \
    for (int j_ = 0; j_ < 4; ++j_) {                                                \
        int s_ = w * 4 + j_;                                                        \
        int rowl_ = 8 * s_ + (l >> 3);                                              \
        int so_ = rowl_ * 256 + (kt_) * 64 + (((l & 7) ^ (rowl_ & 7)) << 3);        \
        gld16(&(src_)[so_], &(dst_)[s_ * 512]);                                     \
    }                                                                               \
} while (0)

#define STAGE_W8(dst_, src_, kt_) do {                                              \
    _Pragma("unroll")                                                               \
    for (int j_ = 0; j_ < 8; ++j_) {                                                \
        int s_ = w * 8 + j_;                                                        \
        int rowl_ = 8 * s_ + (l >> 3);                                              \
        int so_ = rowl_ * 256 + (kt_) * 64 + (((l & 7) ^ (rowl_ & 7)) << 3);        \
        gld16(&(src_)[so_], &(dst_)[s_ * 512]);                                     \
    }                                                                               \
} while (0)

#define GEMM_TILE(buf_, kt_) do {                                                   \
    _Pragma("unroll")                                                               \
    for (int ksl_ = 0; ksl_ < 2; ++ksl_) {                                          \
        _Pragma("unroll")                                                           \
        for (int n_ = 0; n_ < 16; ++n_) {                                           \
            int r_ = n_ * 16 + l15;                                                 \
            int idx_ = r_ * 64 + ((((ksl_)*4 + lg) ^ (r_ & 7)) << 3);               \
            half8 b_ = ldh8(&(buf_)[idx_]);                                         \
            acc[n_] = MFMAH32(ah[(kt_) * 2 + ksl_], b_, acc[n_]);                   \
        }                                                                           \
    }                                                                               \
} while (0)

// ---------------------------------------------------------------------------
// 2. Projections (job 0:Q, 1:K, 2:V).  512 thr, 128 rows/block, grid (64,3).
// ---------------------------------------------------------------------------
__global__ __launch_bounds__(512, 1) void proj3_kernel(
    const float* __restrict__ query, const float* __restrict__ kv,
    const float* __restrict__ rel, const unsigned short* __restrict__ WT,
    const float* __restrict__ bq, const float* __restrict__ bk, const float* __restrict__ bv,
    unsigned short* __restrict__ Qh, unsigned short* __restrict__ Kh,
    unsigned short* __restrict__ Vtmp) {
    const int job = blockIdx.y;
    const float* X = (job == 0) ? query : kv;
    const unsigned short* wg = WT + job * 65536;
    const float* bias = (job == 0) ? bq : (job == 1) ? bk : bv;
    const float* rs = (job == 0) ? nullptr : rel;
    unsigned short* oh = (job == 0) ? Qh : (job == 1) ? Kh : Vtmp;

    __shared__ __align__(16) unsigned short wlds[2][256 * 64];

    const int w = threadIdx.x >> 6, l = threadIdx.x & 63;
    const int l15 = l & 15, lg = l >> 4;
    const int arow = blockIdx.x * 128 + w * 16 + l15;

    half8 ah[8];
#pragma unroll
    for (int ks = 0; ks < 8; ++ks) {
        const float* p = &X[arow * 256 + ks * 32 + lg * 8];
        float4 f0 = *reinterpret_cast<const float4*>(p);
        float4 f1 = *reinterpret_cast<const float4*>(p + 4);
        half8 t;
        t[0] = (_Float16)f0.x; t[1] = (_Float16)f0.y; t[2] = (_Float16)f0.z; t[3] = (_Float16)f0.w;
        t[4] = (_Float16)f1.x; t[5] = (_Float16)f1.y; t[6] = (_Float16)f1.z; t[7] = (_Float16)f1.w;
        ah[ks] = t;
    }
    f32x4 acc[16];
#pragma unroll
    for (int n = 0; n < 16; ++n) acc[n] = (f32x4){0.f, 0.f, 0.f, 0.f};

    STAGE_W(wlds[0], wg, 0);
    __syncthreads();
#pragma unroll
    for (int kt = 0; kt < 4; ++kt) {
        const int cur = kt & 1, nx = cur ^ 1;
        if (kt < 3) STAGE_W(wlds[nx], wg, kt + 1);
        GEMM_TILE(wlds[cur], kt);
        __syncthreads();
    }

    const int orow0 = blockIdx.x * 128 + w * 16 + lg * 4;
    float rsv[4];
#pragma unroll
    for (int r = 0; r < 4; ++r) rsv[r] = rs ? rs[orow0 + r] : 1.0f;
#pragma unroll
    for (int n = 0; n < 16; ++n) {
        const int col = n * 16 + l15;
        const float bn = bias[col];
#pragma unroll
        for (int r = 0; r < 4; ++r)
            oh[(orow0 + r) * 256 + col] = f2h((acc[n][r] + bn) * rsv[r]);
    }
}

// ---------------------------------------------------------------------------
// 3. Transpose V: Vtmp [b][k][256 d] -> Vt [b][st=k/16][256 d][16 k]
// ---------------------------------------------------------------------------
__global__ void transpose_v_kernel(const unsigned short* __restrict__ Vtmp,
                                   unsigned short* __restrict__ Vt) {
    __shared__ unsigned short tile[16][264];
    const int st = blockIdx.x, b = blockIdx.y;
    const int t = threadIdx.x;
#pragma unroll
    for (int it = 0; it < 4; ++it) {
        int idx = it * 256 + t;              // ushort4 units, 1024 total
        int kr = idx >> 6;
        int d4 = (idx & 63) * 4;
        ushort4 v = *reinterpret_cast<const ushort4*>(
            &Vtmp[(size_t)(b * 2048 + st * 16 + kr) * 256 + d4]);
        tile[kr][d4 + 0] = v.x; tile[kr][d4 + 1] = v.y;
        tile[kr][d4 + 2] = v.z; tile[kr][d4 + 3] = v.w;
    }
    __syncthreads();
    {
        const int d = t;
        unsigned int u[8];
#pragma unroll
        for (int k2 = 0; k2 < 8; ++k2)
            u[k2] = (unsigned int)tile[k2 * 2][d] | ((unsigned int)tile[k2 * 2 + 1][d] << 16);
        uint4* dst = reinterpret_cast<uint4*>(&Vt[((size_t)(b * 128 + st) * 256 + d) * 16]);
        dst[0] = (uint4){u[0], u[1], u[2], u[3]};
        dst[1] = (uint4){u[4], u[5], u[6], u[7]};
    }
}

// ---------------------------------------------------------------------------
// 4. Attention pass 1 (R14-proven depth-1).  Grid 512 = 4b x 64qt(32) x 2kh.
//    512 thr = 8 waves = (4 heads) x (2 ks); 32 steps of 16 k-rows/wave.
//    K: gld_lds private dbuf.  V: global->reg, 2 named sets, vmcnt(6).
// ---------------------------------------------------------------------------
__global__ __launch_bounds__(512, 4) void attn_pass1(
    const unsigned short* __restrict__ Qh, const unsigned short* __restrict__ Kh,
    const unsigned short* __restrict__ Vt, const float* __restrict__ rel,
    float* __restrict__ po_a, float* __restrict__ po_b, float* __restrict__ ps) {
    const int bid = blockIdx.x;                       // 0..511
    const int sw = (bid & 7) * 64 + (bid >> 3);       // XCD batch-locality
    const int b = sw >> 7;                            // 0..3
    const int rem = sw & 127;                         // 64qt x 2kh
    const int kh = rem & 1;
    const int q0 = (rem >> 1) * 32;                   // 32-row q tile
    const int tid = threadIdx.x;
    const int w = tid >> 6, h = w & 3, ks = w >> 2;
    const int l = tid & 63, l15 = l & 15, lg = l >> 4;
    const float C2 = 0.18033688011112042f;            // 0.125 * log2(e)

    __shared__ __align__(16) unsigned short ldsK[8][2][1024];   // 32KB
    __shared__ float rel_lr[2048];                              // 8KB
    __shared__ float ssum_sh[2][4][2][16];                      // 1KB

    {   // lr = log2(clamp(rel)): 512 thr x 4 floats
        float4 v = reinterpret_cast<const float4*>(&rel[b * 2048])[tid];
        float* d = &rel_lr[tid * 4];
        d[0] = log2f(fmaxf(v.x, 1e-6f)); d[1] = log2f(fmaxf(v.y, 1e-6f));
        d[2] = log2f(fmaxf(v.z, 1e-6f)); d[3] = log2f(fmaxf(v.w, 1e-6f));
    }

    half8 qf[2][2];                                   // [qs][kd] B-frags
#pragma unroll
    for (int qs = 0; qs < 2; ++qs)
#pragma unroll
        for (int kd = 0; kd < 2; ++kd)
            qf[qs][kd] = ldh8(&Qh[(b * 2048 + q0 + qs * 16 + l15) * 256 +
                                  h * 64 + kd * 32 + lg * 8]);
    __syncthreads();

    const int st0 = kh * 64 + ks * 32;                // 16-row step units

    size_t kb_[2];
    {
        const int swzK = ((l & 7) ^ ((l >> 3) & 7)) << 3;
#pragma unroll
        for (int j = 0; j < 2; ++j) {
            int kr = j * 8 + (l >> 3);
            kb_[j] = (size_t)(b * 2048 + st0 * 16 + kr) * 256 + h * 64 + swzK;
        }
    }
    size_t va_[4];
#pragma unroll
    for (int dc = 0; dc < 4; ++dc)
        va_[dc] = ((size_t)((b * 128 + st0) * 256) + h * 64 + dc * 16 + l15) * 16 + lg * 4;

    unsigned short* myK = &ldsK[w][0][0];
    const int kOff0 = l15 * 64 + ((lg ^ (l15 & 7)) << 3);
    const int kOff1 = l15 * 64 + (((4 + lg) ^ (l15 & 7)) << 3);

#define STGK(buf_, i_) do {                                                         \
    gld16(&Kh[kb_[0] + (size_t)(i_) * 4096], &myK[(buf_) * 1024]);                  \
    gld16(&Kh[kb_[1] + (size_t)(i_) * 4096], &myK[(buf_) * 1024 + 512]);            \
} while (0)
#define VLOADM(dst_, i_) do {                                                       \
    dst_[0] = ldh4(&Vt[va_[0] + (size_t)(i_) * 4096]);                              \
    dst_[1] = ldh4(&Vt[va_[1] + (size_t)(i_) * 4096]);                              \
    dst_[2] = ldh4(&Vt[va_[2] + (size_t)(i_) * 4096]);                              \
    dst_[3] = ldh4(&Vt[va_[3] + (size_t)(i_) * 4096]);                              \
} while (0)

    float ssum0 = 0.f, ssum1 = 0.f;
    f32x4 oacc0[4], oacc1[4];
#pragma unroll
    for (int dc = 0; dc < 4; ++dc) {
        oacc0[dc] = (f32x4){0.f, 0.f, 0.f, 0.f};
        oacc1[dc] = (f32x4){0.f, 0.f, 0.f, 0.f};
    }

#define COMPUTE(step_, BUF_, VF_) do {                                              \
    half8 kf0 = ldh8(&myK[(BUF_) * 1024 + kOff0]);                                  \
    half8 kf1 = ldh8(&myK[(BUF_) * 1024 + kOff1]);                                  \
    f32x4 a0 = (f32x4){0.f, 0.f, 0.f, 0.f}, a1 = a0;                                \
    a0 = MFMAH32(kf0, qf[0][0], a0); a0 = MFMAH32(kf1, qf[0][1], a0);               \
    a1 = MFMAH32(kf0, qf[1][0], a1); a1 = MFMAH32(kf1, qf[1][1], a1);               \
    float4 lr4 = *reinterpret_cast<const float4*>(                                  \
        &rel_lr[(st0 + (step_)) * 16 + lg * 4]);                                    \
    float p00 = exp2f(__builtin_fmaf(a0[0], C2, lr4.x));                            \
    float p01 = exp2f(__builtin_fmaf(a0[1], C2, lr4.y));                            \
    float p02 = exp2f(__builtin_fmaf(a0[2], C2, lr4.z));                            \
    float p03 = exp2f(__builtin_fmaf(a0[3], C2, lr4.w));                            \
    float p10 = exp2f(__builtin_fmaf(a1[0], C2, lr4.x));                            \
    float p11 = exp2f(__builtin_fmaf(a1[1], C2, lr4.y));                            \
    float p12 = exp2f(__builtin_fmaf(a1[2], C2, lr4.z));                            \
    float p13 = exp2f(__builtin_fmaf(a1[3], C2, lr4.w));                            \
    ssum0 += (p00 + p01) + (p02 + p03);                                             \
    ssum1 += (p10 + p11) + (p12 + p13);                                             \
    half4 pa0 = pk4(p00, p01, p02, p03);                                            \
    half4 pa1 = pk4(p10, p11, p12, p13);                                            \
    _Pragma("unroll")                                                               \
    for (int dc = 0; dc < 4; ++dc) {                                                \
        oacc0[dc] = MFMAH16(pa0, VF_[dc], oacc0[dc]);                               \
        oacc1[dc] = MFMAH16(pa1, VF_[dc], oacc1[dc]);                               \
    }                                                                               \
} while (0)

    half4 vfa[4], vfb[4];
    STGK(0, 0);
    VLOADM(vfa, 0);
    for (int i = 0; i < 32; i += 2) {
        STGK(1, i + 1);
        VLOADM(vfb, i + 1);
        asm volatile("s_waitcnt vmcnt(6)" ::: "memory");
        __builtin_amdgcn_sched_barrier(0);
        COMPUTE(i, 0, vfa);
        {
            const int nxt = (i + 2 < 32) ? i + 2 : 31;
            STGK(0, nxt);
            VLOADM(vfa, nxt);
        }
        asm volatile("s_waitcnt vmcnt(6)" ::: "memory");
        __builtin_amdgcn_sched_barrier(0);
        COMPUTE(i + 1, 1, vfb);
    }
    asm volatile("s_waitcnt vmcnt(0)" ::: "memory");
#undef STGK
#undef VLOADM
#undef COMPUTE

    float vr0 = ssum0, vr1 = ssum1;
    vr0 += __shfl_xor(vr0, 16); vr0 += __shfl_xor(vr0, 32);
    vr1 += __shfl_xor(vr1, 16); vr1 += __shfl_xor(vr1, 32);

    __syncthreads();                                  // done with ldsK
    if (l < 16) { ssum_sh[ks][h][0][l] = vr0; ssum_sh[ks][h][1][l] = vr1; }
    float* obuf = (float*)&ldsK[0][0][0];             // [32 q][256 d] = 32KB
    if (ks == 1) {
#pragma unroll
        for (int qs = 0; qs < 2; ++qs)
#pragma unroll
            for (int dc = 0; dc < 4; ++dc)
#pragma unroll
                for (int r = 0; r < 4; ++r)
                    obuf[(qs * 16 + lg * 4 + r) * 256 + h * 64 + dc * 16 + l15] =
                        (qs == 0) ? oacc0[dc][r] : oacc1[dc][r];
    }
    __syncthreads();
    if (ks == 0) {
        const int chunk = b * 2 + kh;                 // 0..7
        float* po = (chunk < 2) ? (po_a + (size_t)chunk * 524288)
                                : (po_b + (size_t)(chunk - 2) * 524288);
#pragma unroll
        for (int qs = 0; qs < 2; ++qs)
#pragma unroll
            for (int dc = 0; dc < 4; ++dc)
#pragma unroll
                for (int r = 0; r < 4; ++r) {
                    const int d = h * 64 + dc * 16 + l15;
                    const int q = qs * 16 + lg * 4 + r;
                    const float mine = (qs == 0) ? oacc0[dc][r] : oacc1[dc][r];
                    po[(size_t)(q0 + q) * 256 + d] = mine + obuf[q * 256 + d];
                }
        if (l < 16) {
            ps[(chunk * 4 + h) * 2048 + q0 + l] =
                ssum_sh[0][h][0][l] + ssum_sh[1][h][0][l];
            ps[(chunk * 4 + h) * 2048 + q0 + 16 + l] =
                ssum_sh[0][h][1][l] + ssum_sh[1][h][1][l];
        }
    }
}

// ---------------------------------------------------------------------------
// 5. Combine k-half partials: AO = (po0+po1)/s (fp16), sinv_ws = 1/s.
// ---------------------------------------------------------------------------
__global__ __launch_bounds__(256) void combine_kernel(
    const float* __restrict__ po_a, const float* __restrict__ po_b,
    const float* __restrict__ ps, unsigned short* __restrict__ AO,
    float* __restrict__ sinv_ws) {
    const int t = blockIdx.x * 256 + threadIdx.x;
    const int d4 = t & 63;
    const int bq = t >> 6;
    const int q = bq & 2047;
    const int b = bq >> 11;
    const int d0 = d4 * 4, h = d0 >> 6;
    const int c0 = b * 2, c1 = b * 2 + 1;
    const float* p0 = (c0 < 2) ? po_a + (size_t)c0 * 524288 : po_b + (size_t)(c0 - 2) * 524288;
    const float* p1 = (c1 < 2) ? po_a + (size_t)c1 * 524288 : po_b + (size_t)(c1 - 2) * 524288;
    float4 x = *reinterpret_cast<const float4*>(&p0[(size_t)q * 256 + d0]);
    float4 y = *reinterpret_cast<const float4*>(&p1[(size_t)q * 256 + d0]);
    float s = ps[(c0 * 4 + h) * 2048 + q] + ps[(c1 * 4 + h) * 2048 + q];
    float si = 1.0f / s;
    ushort4 o;
    o.x = f2h((x.x + y.x) * si); o.y = f2h((x.y + y.y) * si);
    o.z = f2h((x.z + y.z) * si); o.w = f2h((x.w + y.w) * si);
    *reinterpret_cast<ushort4*>(&AO[((size_t)(b * 2048 + q)) * 256 + d0]) = o;
    if (d4 == (h << 4)) sinv_ws[(b * 4 + h) * 2048 + q] = si;
}

// ---------------------------------------------------------------------------
// 6. Attention pass 2: attn_mean (R14 structure, sinv-based lsi).
// ---------------------------------------------------------------------------
__global__ __launch_bounds__(256, 4) void attn_mean_kernel(
    const unsigned short* __restrict__ Qh, const unsigned short* __restrict__ Kh,
    const float* __restrict__ rel, const float* __restrict__ sinv_ws,
    float* __restrict__ attn_mean) {
    const int kslice = blockIdx.x >> 7;               // 0..7
    const int inner = blockIdx.x & 127;
    const int sw = (inner & 7) * 16 + (inner >> 3);   // XCD batch-locality
    const int b = sw >> 5;
    const int q0 = (sw & 31) * 64;                    // 64-row q tile
    const int tid = threadIdx.x;
    const int w = tid >> 6;                           // wave = qs (0..3)
    const int l = tid & 63, l15 = l & 15, lg = l >> 4;
    const int kb = b * 2048;
    const float C2 = 0.18033688011112042f;

    __shared__ __align__(16) unsigned short ldsK[2][8192];      // 32KB
    __shared__ float rel_lr[2048];                              // 8KB

    {
        float4 v0 = reinterpret_cast<const float4*>(&rel[b * 2048])[tid * 2];
        float4 v1 = reinterpret_cast<const float4*>(&rel[b * 2048])[tid * 2 + 1];
        float* d = &rel_lr[tid * 8];
        d[0] = log2f(fmaxf(v0.x, 1e-6f)); d[1] = log2f(fmaxf(v0.y, 1e-6f));
        d[2] = log2f(fmaxf(v0.z, 1e-6f)); d[3] = log2f(fmaxf(v0.w, 1e-6f));
        d[4] = log2f(fmaxf(v1.x, 1e-6f)); d[5] = log2f(fmaxf(v1.y, 1e-6f));
        d[6] = log2f(fmaxf(v1.z, 1e-6f)); d[7] = log2f(fmaxf(v1.w, 1e-6f));
    }

    half8 qf[4][2];
    {
        const int qrow = b * 2048 + q0 + w * 16 + l15;
#pragma unroll
        for (int h = 0; h < 4; ++h)
#pragma unroll
            for (int kd = 0; kd < 2; ++kd)
                qf[h][kd] = ldh8(&Qh[qrow * 256 + h * 64 + kd * 32 + lg * 8]);
    }
    float lsi[4][4];
#pragma unroll
    for (int h = 0; h < 4; ++h)
#pragma unroll
        for (int r4 = 0; r4 < 4; ++r4)
            lsi[h][r4] = log2f(sinv_ws[(b * 4 + h) * 2048 + q0 + w * 16 + lg * 4 + r4]) - 2.0f;

    size_t kmb[4];
    {
#pragma unroll
        for (int j = 0; j < 4; ++j) {
            int s_ = w * 4 + j;
            int r_ = 2 * s_ + (l >> 5);
            kmb[j] = (size_t)(kb + r_) * 256 + (((l & 31) ^ (r_ & 7)) << 3);
        }
    }
#define STAGE_KM2(dst_, off_) do {                                                  \
    gld16(&Kh[kmb[0] + (off_)], &(dst_)[(w * 4 + 0) * 512]);                        \
    gld16(&Kh[kmb[1] + (off_)], &(dst_)[(w * 4 + 1) * 512]);                        \
    gld16(&Kh[kmb[2] + (off_)], &(dst_)[(w * 4 + 2) * 512]);                        \
    gld16(&Kh[kmb[3] + (off_)], &(dst_)[(w * 4 + 3) * 512]);                        \
} while (0)

    __syncthreads();

    const int kt0 = kslice * 8;
    size_t moff = (size_t)kt0 * 8192;
    STAGE_KM2(ldsK[0], moff);
    for (int ki = 0; ki < 8; ++ki) {
        const int kt = kt0 + ki;
        const int cur = ki & 1, nx = cur ^ 1;
        if (ki < 7) {
            STAGE_KM2(ldsK[nx], moff + 8192);
            moff += 8192;
            asm volatile("s_waitcnt vmcnt(4)" ::: "memory");
        } else {
            asm volatile("s_waitcnt vmcnt(0)" ::: "memory");
        }
        asm volatile("s_barrier" ::: "memory");       // buf[cur] ready
        __builtin_amdgcn_sched_barrier(0);
#pragma unroll
        for (int kc = 0; kc < 2; ++kc) {
            const int r = kc * 16 + l15;
            const int rx = r & 7;
            f32x4 a[4];
#pragma unroll
            for (int h = 0; h < 4; ++h) {
                half8 kf0 = ldh8(&ldsK[cur][r * 256 + (((h * 8 + lg) ^ rx) << 3)]);
                half8 kf1 = ldh8(&ldsK[cur][r * 256 + (((h * 8 + 4 + lg) ^ rx) << 3)]);
                f32x4 t = (f32x4){0.f, 0.f, 0.f, 0.f};
                t = MFMAH32(qf[h][0], kf0, t);
                t = MFMAH32(qf[h][1], kf1, t);
                a[h] = t;
            }
            const float lr = rel_lr[kt * 32 + kc * 16 + l15];
            const size_t kcol = (size_t)(kt * 32 + kc * 16 + l15);
#pragma unroll
            for (int r4 = 0; r4 < 4; ++r4) {
                float m = exp2f(__builtin_fmaf(a[0][r4], C2, lsi[0][r4]) + lr)
                        + exp2f(__builtin_fmaf(a[1][r4], C2, lsi[1][r4]) + lr)
                        + exp2f(__builtin_fmaf(a[2][r4], C2, lsi[2][r4]) + lr)
                        + exp2f(__builtin_fmaf(a[3][r4], C2, lsi[3][r4]) + lr);
                attn_mean[(size_t)(b * 2048 + q0 + w * 16 + lg * 4 + r4) * 2048 + kcol] = m;
            }
        }
        asm volatile("s_waitcnt lgkmcnt(0)\n\ts_barrier" ::: "memory");  // reads done
    }
#undef STAGE_KM2
}

// ---------------------------------------------------------------------------
// 7. out = AO @ Wo + bo.  256 thr, BM=64, grid 128.
// ---------------------------------------------------------------------------
__global__ __launch_bounds__(256, 2) void final_kernel(
    const unsigned short* __restrict__ AO, const unsigned short* __restrict__ WoT,
    const float* __restrict__ bo, float* __restrict__ out) {
    __shared__ __align__(16) unsigned short wlds[2][256 * 64];

    const int w = threadIdx.x >> 6, l = threadIdx.x & 63;
    const int l15 = l & 15, lg = l >> 4;
    const int arow = blockIdx.x * 64 + w * 16 + l15;

    half8 ah[8];
#pragma unroll
    for (int ks = 0; ks < 8; ++ks)
        ah[ks] = ldh8(&AO[arow * 256 + ks * 32 + lg * 8]);
    f32x4 acc[16];
#pragma unroll
    for (int n = 0; n < 16; ++n) acc[n] = (f32x4){0.f, 0.f, 0.f, 0.f};

    STAGE_W8(wlds[0], WoT, 0);
    __syncthreads();
#pragma unroll
    for (int kt = 0; kt < 4; ++kt) {
        const int cur = kt & 1, nx = cur ^ 1;
        if (kt < 3) STAGE_W8(wlds[nx], WoT, kt + 1);
        GEMM_TILE(wlds[cur], kt);
        __syncthreads();
    }

    const int orow0 = blockIdx.x * 64 + w * 16 + lg * 4;
#pragma unroll
    for (int n = 0; n < 16; ++n) {
        const int col = n * 16 + l15;
        const float bn = bo[col];
#pragma unroll
        for (int r = 0; r < 4; ++r)
            out[(orow0 + r) * 256 + col] = acc[n][r] + bn;
    }
}

// ---------------------------------------------------------------------------
extern "C" void kernel_launch(void* const* d_in, const int* in_sizes, int n_in,
                              void* d_out, int out_size, void* d_ws, size_t ws_size,
                              hipStream_t stream) {
    const float* query = (const float*)d_in[0];
    const float* kv    = (const float*)d_in[1];
    const float* rel   = (const float*)d_in[2];
    const float* Wq    = (const float*)d_in[3];
    const float* bq    = (const float*)d_in[4];
    const float* Wk    = (const float*)d_in[5];
    const float* bk    = (const float*)d_in[6];
    const float* Wv    = (const float*)d_in[7];
    const float* bv    = (const float*)d_in[8];
    const float* Wo    = (const float*)d_in[9];
    const float* bo    = (const float*)d_in[10];

    char* ws = (char*)d_ws;
    unsigned short* WT   = (unsigned short*)(ws + 0);          // 512KB
    unsigned short* Qh   = (unsigned short*)(ws + 524288);     // 4MB
    unsigned short* Kh   = (unsigned short*)(ws + 4718592);    // 4MB
    unsigned short* Vtmp = (unsigned short*)(ws + 8912896);    // 4MB (po_a after transpose)
    unsigned short* Vt   = (unsigned short*)(ws + 13107200);   // 4MB
    unsigned short* AO   = (unsigned short*)(ws + 17301504);   // 4MB
    float*          sinv = (float*)(ws + 21495808);            // 128KB
    float*          ps   = (float*)(ws + 21626880);            // 256KB (8 chunks x 4 h)
    float*          po_b = (float*)(ws + 21889024);            // 12MB (chunks 2..7)
    float*          po_a = (float*)Vtmp;                       // chunks 0,1 overlay (4MB)

    float* out = (float*)d_out;
    float* attn_mean = (float*)d_out + 2097152;

    wsplit_kernel<<<1024, 256, 0, stream>>>(Wq, Wk, Wv, Wo, WT);
    proj3_kernel<<<dim3(64, 3), 512, 0, stream>>>(query, kv, rel, WT,
                                                  bq, bk, bv, Qh, Kh, Vtmp);
    transpose_v_kernel<<<dim3(128, 4), 256, 0, stream>>>(Vtmp, Vt);
    attn_pass1<<<512, 512, 0, stream>>>(Qh, Kh, Vt, rel, po_a, po_b, ps);
    combine_kernel<<<2048, 256, 0, stream>>>(po_a, po_b, ps, AO, sinv);
    attn_mean_kernel<<<1024, 256, 0, stream>>>(Qh, Kh, rel, sinv, attn_mean);
    final_kernel<<<128, 256, 0, stream>>>(AO, WT + 3 * 65536, bo, out);
}